// Round 8
// baseline (247.882 us; speedup 1.0000x reference)
//
#include <hip/hip_runtime.h>
#include <hip/hip_bf16.h>
#include <math.h>

// (B, D, H, W, K) = (32, 256, 64, 64, 64); N = H*W = 4096
#define BB 32
#define DD 256
#define NN 4096
#define KK 64
#define EPSV 1e-8f
#define XSTR 264   // xnd row stride (shorts): 528 B = 16B-aligned, bank-rotating

typedef __attribute__((ext_vector_type(8))) short short8;   // 8 bf16
typedef __attribute__((ext_vector_type(4))) float f32x4;

__device__ __forceinline__ unsigned int bf16pair(float a, float b) {
    __hip_bfloat162 h = __float22bfloat162_rn(make_float2(a, b));  // v_cvt_pk_bf16_f32 (RNE)
    return *(unsigned int*)&h;
}
__device__ __forceinline__ unsigned short bf16one(float a) {
    unsigned int ua = __float_as_uint(a);
    ua += 0x7fffu + ((ua >> 16) & 1u);
    return (unsigned short)(ua >> 16);
}

// ---------- K0: normalized bf16 codewords -> ws (L1-resident, 32 KB) ----------
__global__ __launch_bounds__(256) void k_prep(const float* __restrict__ C,
                                              unsigned short* __restrict__ Cnb) {
    __shared__ float rcn_s[KK];
    int t = threadIdx.x;
    if (t < KK) {
        const float4* c4 = (const float4*)(C + t * DD);
        float ss = 0.f;
#pragma unroll 8
        for (int i = 0; i < DD / 4; i++) {
            float4 v = c4[i];
            ss = fmaf(v.x, v.x, ss);
            ss = fmaf(v.y, v.y, ss);
            ss = fmaf(v.z, v.z, ss);
            ss = fmaf(v.w, v.w, ss);
        }
        rcn_s[t] = 1.f / fmaxf(sqrtf(ss), EPSV);
    }
    __syncthreads();
    int k = t >> 2, d0 = (t & 3) * 64;
    float r = rcn_s[k];
#pragma unroll
    for (int j = 0; j < 64; j += 4) {
        float4 v = *(const float4*)(C + k * DD + d0 + j);
        uint2 u;
        u.x = bf16pair(v.x * r, v.y * r);
        u.y = bf16pair(v.z * r, v.w * r);
        *(uint2*)(Cnb + k * DD + d0 + j) = u;
    }
}

// stage one 4d x 4n register subtile into xdn (d-major) and xnd (n-major)
__device__ __forceinline__ void stage_group(int dbase, int n4, const float4* rr,
                                            unsigned short* xnd_s, unsigned short* xdn_s,
                                            f32x4& ssn) {
    float4 r0 = rr[0], r1 = rr[1], r2 = rr[2], r3 = rr[3];
    ssn.x = fmaf(r0.x, r0.x, ssn.x); ssn.x = fmaf(r1.x, r1.x, ssn.x);
    ssn.x = fmaf(r2.x, r2.x, ssn.x); ssn.x = fmaf(r3.x, r3.x, ssn.x);
    ssn.y = fmaf(r0.y, r0.y, ssn.y); ssn.y = fmaf(r1.y, r1.y, ssn.y);
    ssn.y = fmaf(r2.y, r2.y, ssn.y); ssn.y = fmaf(r3.y, r3.y, ssn.y);
    ssn.z = fmaf(r0.z, r0.z, ssn.z); ssn.z = fmaf(r1.z, r1.z, ssn.z);
    ssn.z = fmaf(r2.z, r2.z, ssn.z); ssn.z = fmaf(r3.z, r3.z, ssn.z);
    ssn.w = fmaf(r0.w, r0.w, ssn.w); ssn.w = fmaf(r1.w, r1.w, ssn.w);
    ssn.w = fmaf(r2.w, r2.w, ssn.w); ssn.w = fmaf(r3.w, r3.w, ssn.w);
#pragma unroll
    for (int j = 0; j < 4; j++) {  // xdn: row d, 4 consecutive n -> b64
        int d = dbase + j;
        uint2 u;
        u.x = bf16pair(rr[j].x, rr[j].y);
        u.y = bf16pair(rr[j].z, rr[j].w);
        *(uint2*)(xdn_s + d * 64 + ((((n4 >> 3) ^ (d & 7)) << 3) | (n4 & 7))) = u;
    }
    {  // xnd: row n, 4 consecutive d -> b64 (register transpose)
        float col[4][4] = {{r0.x, r1.x, r2.x, r3.x},
                           {r0.y, r1.y, r2.y, r3.y},
                           {r0.z, r1.z, r2.z, r3.z},
                           {r0.w, r1.w, r2.w, r3.w}};
#pragma unroll
        for (int j = 0; j < 4; j++) {
            int n = n4 + j;
            uint2 u;
            u.x = bf16pair(col[j][0], col[j][1]);
            u.y = bf16pair(col[j][2], col[j][3]);
            int blk = (dbase >> 3) ^ ((n >> 2) & 3);
            *(uint2*)(xnd_s + n * XSTR + (blk << 3) + (dbase & 7)) = u;
        }
    }
}

// ---------------- fused: L-GEMM -> softmax -> agg-GEMM ----------------
// grid 512 = 32 b x 16 chunks of 256 n; 4 passes of 64 n; 4 waves.
// R8: Ln[n][k] orientation — wave w owns n-slice [16w,16w+16) with ALL 64 k:
//   A-frag = X from xnd (LDS b128), B-frag = normalized bf16 codewords from
//   global (L1-hot 32 KB, per-pass ks rotation defeats LICM hoisting).
//   Softmax fully in-wave (shfl over c-bits) -> red_m/red_s rounds and
//   barrier D eliminated: 3 barriers/pass. Freed cnf regs fund pre[16]
//   full-pass-ahead prefetch (no cur exposure). agg-GEMM unchanged (d-split).
__global__ __launch_bounds__(256, 2) void k_fused(const float* __restrict__ X,
                                                  const unsigned short* __restrict__ Cnb,
                                                  float* __restrict__ P,
                                                  float* __restrict__ Sp) {
    __shared__ unsigned short xnd_s[64 * XSTR];  // [n][d] bf16, 33792 B
    __shared__ unsigned short xdn_s[DD * 64];    // [d][n] bf16, 32768 B
    __shared__ unsigned short at_s[KK * 72];     // [k][n] bf16, 9216 B
    __shared__ float rn4[4 * 64];                // per-wave partial ||x_n||^2
    __shared__ float s_red[4 * 64];              // per-wave S partials
    // total 77824 B -> 2 blocks/CU

    int t = threadIdx.x;
    int b = blockIdx.x >> 4, chunk = blockIdx.x & 15;
    int w = t >> 6, lane = t & 63, c = lane & 15, g = lane >> 4;
    int q = t >> 4;  // staging d-group 0..15
    int n4 = c * 4;
    int c7 = c & 7;

    const float* Xb = X + (size_t)b * DD * NN + chunk * 256;

    // ---- initial prefetch (pass 0): 16 float4 = 64 VGPRs, full tile ahead ----
    float4 pre[16];
#pragma unroll
    for (int i = 0; i < 4; i++) {
        const float* xb = Xb + (size_t)(q * 4 + 64 * i) * NN + n4;
#pragma unroll
        for (int j = 0; j < 4; j++) pre[i * 4 + j] = *(const float4*)(xb + (size_t)j * NN);
    }

    f32x4 eacc[4][4];  // [dtile][ktile] Et accumulator, d = 64w + 16dt + 4g + r
#pragma unroll
    for (int dt = 0; dt < 4; dt++)
#pragma unroll
        for (int kt = 0; kt < 4; kt++) eacc[dt][kt] = (f32x4){0.f, 0.f, 0.f, 0.f};
    float s_acc[4] = {0.f, 0.f, 0.f, 0.f};  // per-kt partial S for k = 16kt + c

    for (int p = 0; p < 4; p++) {
        __syncthreads();  // (A) prev-pass xnd/xdn/at reads complete

        // ---- stage from pre (arrived a full pass ago: zero wait) ----
        f32x4 ssn = (f32x4){0.f, 0.f, 0.f, 0.f};
#pragma unroll
        for (int i = 0; i < 4; i++)
            stage_group(q * 4 + 64 * i, n4, &pre[i * 4], xnd_s, xdn_s, ssn);

        // ---- issue NEXT pass's full prefetch: in flight across everything ----
        if (p < 3) {
#pragma unroll
            for (int i = 0; i < 4; i++) {
                const float* xb = Xb + (size_t)(q * 4 + 64 * i) * NN + (p + 1) * 64 + n4;
#pragma unroll
                for (int j = 0; j < 4; j++) pre[i * 4 + j] = *(const float4*)(xb + (size_t)j * NN);
            }
        }

        // ---- row-norm partials: reduce over q-within-wave via shfl ----
        ssn.x += __shfl_xor(ssn.x, 16); ssn.x += __shfl_xor(ssn.x, 32);
        ssn.y += __shfl_xor(ssn.y, 16); ssn.y += __shfl_xor(ssn.y, 32);
        ssn.z += __shfl_xor(ssn.z, 16); ssn.z += __shfl_xor(ssn.z, 32);
        ssn.w += __shfl_xor(ssn.w, 16); ssn.w += __shfl_xor(ssn.w, 32);
        if (g == 0) *(f32x4*)(rn4 + w * 64 + n4) = ssn;

        __syncthreads();  // (B) staging + rn4 visible

        // ---- L-GEMM: Ln[16 n (=16w+c rows)][64 k], B from global Cn (L1) ----
        f32x4 lacc[4];
#pragma unroll
        for (int kt = 0; kt < 4; kt++) lacc[kt] = (f32x4){0.f, 0.f, 0.f, 0.f};
        const unsigned short* xr = xnd_s + (16 * w + c) * XSTR;
#pragma unroll
        for (int ks = 0; ks < 8; ks++) {
            int kss = (ks + 2 * p) & 7;  // per-pass rotation: defeats LICM hoist
            short8 af = *(const short8*)(xr + (((4 * kss + g) ^ (c >> 2)) << 3));
#pragma unroll
            for (int kt = 0; kt < 4; kt++) {
                short8 bf = *(const short8*)(Cnb + (16 * kt + c) * DD + 32 * kss + 8 * g);
                lacc[kt] = __builtin_amdgcn_mfma_f32_16x16x32_bf16(af, bf, lacc[kt], 0, 0, 0);
            }
        }

        // ---- softmax fully in-wave (no max-subtract: cosine in [-1,1]) ----
        // lane holds (n = 16w + 4g + r, k = 16kt + c); denom: sum over kt (in-
        // lane) + c (shfl_xor 1/2/4/8, g-bits untouched).
        float rnv[4];
#pragma unroll
        for (int r = 0; r < 4; r++) {
            int n = 16 * w + 4 * g + r;
            float ssq = rn4[n] + rn4[64 + n] + rn4[128 + n] + rn4[192 + n];
            rnv[r] = 1.f / fmaxf(sqrtf(ssq), EPSV);
        }
        float lv[4][4];  // [kt][r]
        float sden[4] = {0.f, 0.f, 0.f, 0.f};
#pragma unroll
        for (int kt = 0; kt < 4; kt++)
#pragma unroll
            for (int r = 0; r < 4; r++) {
                lv[kt][r] = __expf(lacc[kt][r] * rnv[r]);
                sden[r] += lv[kt][r];
            }
#pragma unroll
        for (int r = 0; r < 4; r++) {
            sden[r] += __shfl_xor(sden[r], 1);
            sden[r] += __shfl_xor(sden[r], 2);
            sden[r] += __shfl_xor(sden[r], 4);
            sden[r] += __shfl_xor(sden[r], 8);
            sden[r] = 1.f / sden[r];
        }
#pragma unroll
        for (int kt = 0; kt < 4; kt++) {
            int k = 16 * kt + c;
#pragma unroll
            for (int r = 0; r < 4; r++) {
                float a = lv[kt][r] * sden[r];
                s_acc[kt] += a;
                int n = 16 * w + 4 * g + r;
                at_s[k * 72 + ((((n >> 3) ^ (k & 7)) << 3) | (n & 7))] = bf16one(a);
            }
        }
        __syncthreads();  // (E) at_s visible

        // ---- agg-GEMM: Et[d = 64w..][k] += sum_n X[n][d] * A[n][k] ----
#pragma unroll
        for (int ks2 = 0; ks2 < 2; ks2++) {
            short8 bk[4];
#pragma unroll
            for (int kt = 0; kt < 4; kt++) {
                int k = kt * 16 + c;
                bk[kt] = *(const short8*)(at_s + k * 72 + (((4 * ks2 + g) ^ (k & 7)) << 3));
            }
#pragma unroll
            for (int dt = 0; dt < 4; dt++) {
                int d = w * 64 + dt * 16 + c;
                short8 af = *(const short8*)(xdn_s + d * 64 + (((4 * ks2 + g) ^ c7) << 3));
#pragma unroll
                for (int kt = 0; kt < 4; kt++)
                    eacc[dt][kt] =
                        __builtin_amdgcn_mfma_f32_16x16x32_bf16(af, bk[kt], eacc[dt][kt], 0, 0, 0);
            }
        }
    }

    // ---- epilogue: partials P[block][d][k] + per-block S ----
    float* Pb = P + (size_t)blockIdx.x * (DD * KK);
#pragma unroll
    for (int dt = 0; dt < 4; dt++)
#pragma unroll
        for (int kt = 0; kt < 4; kt++)
#pragma unroll
            for (int r = 0; r < 4; r++) {
                int d = w * 64 + dt * 16 + 4 * g + r;
                Pb[d * 64 + kt * 16 + c] = eacc[dt][kt][r];
            }
    // S: s_acc[kt] covers this wave's 16 n for k = 16kt + c; sum quads then waves
#pragma unroll
    for (int kt = 0; kt < 4; kt++) {
        float v = s_acc[kt];
        v += __shfl_xor(v, 16);
        v += __shfl_xor(v, 32);
        if (g == 0) s_red[w * 64 + 16 * kt + c] = v;
    }
    __syncthreads();
    if (t < 64) Sp[blockIdx.x * 64 + t] = s_red[t] + s_red[64 + t] + s_red[128 + t] + s_red[192 + t];
}

// ---------- finalize: sum 16 partials, subtract S*C ----------
__global__ __launch_bounds__(256) void k_fin(const float* __restrict__ P,
                                             const float* __restrict__ Sp,
                                             const float* __restrict__ C,
                                             float* __restrict__ out) {
    int idx = blockIdx.x * 256 + threadIdx.x;  // 524288 total
    int b = idx >> 14;
    int r = idx & 16383;
    int d = r >> 6;
    int k = r & 63;  // consecutive threads -> consecutive k: coalesced P reads
    float e = 0.f, s = 0.f;
    int base = b * 16;
#pragma unroll
    for (int cc = 0; cc < 16; cc++) {
        e += P[(size_t)(base + cc) * (DD * KK) + d * 64 + k];
        s += Sp[(base + cc) * 64 + k];
    }
    out[(size_t)(b * 64 + k) * 256 + d] = e - s * C[k * 256 + d];
}

// ---------- launch ----------
extern "C" void kernel_launch(void* const* d_in, const int* in_sizes, int n_in,
                              void* d_out, int out_size, void* d_ws, size_t ws_size,
                              hipStream_t stream) {
    const float* X = (const float*)d_in[0];
    const float* C = (const float*)d_in[1];
    float* out = (float*)d_out;
    unsigned char* ws = (unsigned char*)d_ws;

    // ws: Cnb bf16 32768 B | Sp 512*64*4 = 131072 B | P 512*256*64*4 = 33.5 MB
    unsigned short* Cnb = (unsigned short*)ws;
    float* Sp = (float*)(ws + 32768);
    float* P = (float*)(ws + 32768 + 131072);

    k_prep<<<1, 256, 0, stream>>>(C, Cnb);
    k_fused<<<512, 256, 0, stream>>>(X, Cnb, P, Sp);
    k_fin<<<2048, 256, 0, stream>>>(P, Sp, C, out);
}